// Round 5
// baseline (26.575 us; speedup 1.0000x reference)
//
#include <hip/hip_runtime.h>

#define IMG 512
#define CH_STRIDE (IMG * IMG)   // 262144

__device__ __forceinline__ float4 fmin4(float4 a, float4 b) {
    float4 r;
    r.x = fminf(a.x, b.x); r.y = fminf(a.y, b.y);
    r.z = fminf(a.z, b.z); r.w = fminf(a.w, b.w);
    return r;
}

// G(g): outputs k=0..3 -> min(mflat[k+1 .. k+15]) over u0..u4 = v[g..g+4]
__device__ __forceinline__ float4 hgroup(float4 u0, float4 u1, float4 u2,
                                         float4 u3, float4 u4) {
    float4 m4 = fmin4(u1, fmin4(u2, u3));
    float common = fminf(fminf(m4.x, m4.y), fminf(m4.z, m4.w));
    float pz = fminf(u0.z, u0.w);
    float sz = fminf(u4.x, u4.y);
    float4 o;
    o.x = fminf(common, fminf(u0.y, pz));
    o.y = fminf(common, fminf(pz, u4.x));
    o.z = fminf(common, fminf(u0.w, sz));
    o.w = fminf(common, fminf(sz, u4.z));
    return o;
}

// ---------------- Kernel 1: channel-min + horizontal 15-min (streaming) ----
// One thread per (img, row, 8-col group). 21 vector loads, ~60 mins, 2 stores.
__global__ __launch_bounds__(256)
void hpass(const float* __restrict__ x, float* __restrict__ hmin) {
    int idx = blockIdx.x * 256 + threadIdx.x;   // 16*512*64 = 524288
    int t   = idx & 63;            // 8-col group, out cols 8t..8t+7
    int rr  = idx >> 6;
    int row = rr & 511;
    int img = rr >> 9;

    int bb = 8 * t - 8;
    bb = bb < 0 ? 0 : (bb > IMG - 28 ? IMG - 28 : bb);   // only t=0,62,63 clamp
    const float* p = x + img * 3 * CH_STRIDE + row * IMG + bb;

    float4 A0 = *(const float4*)(p +  0), A1 = *(const float4*)(p +  4),
           A2 = *(const float4*)(p +  8), A3 = *(const float4*)(p + 12),
           A4 = *(const float4*)(p + 16), A5 = *(const float4*)(p + 20),
           A6 = *(const float4*)(p + 24);
    const float* q = p + CH_STRIDE;
    float4 B0 = *(const float4*)(q +  0), B1 = *(const float4*)(q +  4),
           B2 = *(const float4*)(q +  8), B3 = *(const float4*)(q + 12),
           B4 = *(const float4*)(q + 16), B5 = *(const float4*)(q + 20),
           B6 = *(const float4*)(q + 24);
    const float* s2 = p + 2 * CH_STRIDE;
    float4 C0 = *(const float4*)(s2 +  0), C1 = *(const float4*)(s2 +  4),
           C2 = *(const float4*)(s2 +  8), C3 = *(const float4*)(s2 + 12),
           C4 = *(const float4*)(s2 + 16), C5 = *(const float4*)(s2 + 20),
           C6 = *(const float4*)(s2 + 24);

    float4 v0 = fmin4(fmin4(A0, B0), C0);
    float4 v1 = fmin4(fmin4(A1, B1), C1);
    float4 v2 = fmin4(fmin4(A2, B2), C2);
    float4 v3 = fmin4(fmin4(A3, B3), C3);
    float4 v4 = fmin4(fmin4(A4, B4), C4);
    float4 v5 = fmin4(fmin4(A5, B5), C5);
    float4 v6 = fmin4(fmin4(A6, B6), C6);

    float4 o0, o1;
    if (t == 0) {
        // bb=0, m[j]=col j; out col k (0..7) = min m[0 .. k+7]  (reflect-prefix)
        float pm0 = fminf(fminf(fminf(v0.x, v0.y), fminf(v0.z, v0.w)),
                          fminf(fminf(v1.x, v1.y), fminf(v1.z, v1.w)));  // m0..7
        float pm1 = fminf(pm0, v2.x);
        float pm2 = fminf(pm1, v2.y);
        float pm3 = fminf(pm2, v2.z);
        float pm4 = fminf(pm3, v2.w);
        float pm5 = fminf(pm4, v3.x);
        float pm6 = fminf(pm5, v3.y);
        float pm7 = fminf(pm6, v3.z);
        o0 = make_float4(pm0, pm1, pm2, pm3);
        o1 = make_float4(pm4, pm5, pm6, pm7);
    } else if (t == 62) {
        // clamped bb=484 (shift d=4): out col 496+k = min m[k+5 .. k+19]
        o0 = hgroup(v1, v2, v3, v4, v5);
        o1 = hgroup(v2, v3, v4, v5, v6);
    } else if (t == 63) {
        // bb=484: out col 504+k = min m[13+k .. 27]  (reflect-suffix)
        float sm7 = fminf(fminf(fminf(v5.x, v5.y), fminf(v5.z, v5.w)),
                          fminf(fminf(v6.x, v6.y), fminf(v6.z, v6.w)));  // m20..27
        float sm6 = fminf(sm7, v4.w);
        float sm5 = fminf(sm6, v4.z);
        float sm4 = fminf(sm5, v4.y);
        float sm3 = fminf(sm4, v4.x);
        float sm2 = fminf(sm3, v3.w);
        float sm1 = fminf(sm2, v3.z);
        float sm0 = fminf(sm1, v3.y);
        o0 = make_float4(sm0, sm1, sm2, sm3);
        o1 = make_float4(sm4, sm5, sm6, sm7);
    } else {
        // interior: out col 8t+k = min m[k+1 .. k+15]
        o0 = hgroup(v0, v1, v2, v3, v4);
        o1 = hgroup(v1, v2, v3, v4, v5);
    }

    float* op = hmin + img * CH_STRIDE + row * IMG + 8 * t;
    *(float4*)(op)     = o0;
    *(float4*)(op + 4) = o1;
}

// ---------------- Kernel 2: vertical 15-min, LDS-tiled ---------------------
// Block: 256 threads, tile 128 cols x 32 out rows; stage 46 rows in LDS.
#define VROWS 32
#define VSH   46
__global__ __launch_bounds__(256)
void vpass(const float* __restrict__ hmin, float* __restrict__ out) {
    __shared__ float sm[VSH][128];   // 23552 B

    const int tid = threadIdx.x;
    const int bx  = blockIdx.x;   // col strip 0..3
    const int by  = blockIdx.y;   // row block 0..15
    const int b   = blockIdx.z;   // img

    const int r0 = by * VROWS;
    const float* src = hmin + b * CH_STRIDE + bx * 128;

    // stage rows r0-7 .. r0+38 (reflect at image edges), fully coalesced
    #pragma unroll
    for (int it = 0; it < 6; ++it) {
        int i = tid + it * 256;
        if (i < VSH * 32) {
            int r  = i >> 5;
            int c4 = i & 31;
            int gr = r0 - 7 + r;
            gr = gr < 0 ? -gr : (gr > IMG - 1 ? 2 * (IMG - 1) - gr : gr);
            *(float4*)&sm[r][4 * c4] = *(const float4*)(src + gr * IMG + 4 * c4);
        }
    }
    __syncthreads();

    // each thread: 4 out rows x 4 cols; out row r0+j uses sm rows j..j+14
    const int c4 = tid & 31;
    const int rb = (tid >> 5) * 4;

    float4 w[18];
    #pragma unroll
    for (int i = 0; i < 18; ++i) w[i] = *(const float4*)&sm[rb + i][4 * c4];

    float4 ca = fmin4(fmin4(w[3],  w[4]),  fmin4(w[5],  w[6]));
    float4 cb = fmin4(fmin4(w[7],  w[8]),  fmin4(w[9],  w[10]));
    float4 cc = fmin4(fmin4(w[11], w[12]), fmin4(w[13], w[14]));
    float4 common = fmin4(ca, fmin4(cb, cc));
    float4 pp = fmin4(w[1], w[2]);
    float4 ss = fmin4(w[15], w[16]);

    float* ob = out + b * CH_STRIDE + (r0 + rb) * IMG + bx * 128 + 4 * c4;
    *(float4*)(ob)           = fmin4(common, fmin4(w[0], pp));
    *(float4*)(ob + IMG)     = fmin4(common, fmin4(pp, w[15]));
    *(float4*)(ob + 2 * IMG) = fmin4(common, fmin4(w[2], ss));
    *(float4*)(ob + 3 * IMG) = fmin4(common, fmin4(ss, w[17]));
}

// ---------------- Fallback fused kernel (round-3, known-correct) -----------
#define KER    15
#define PAD    7
#define TILE_W 64
#define TILE_H 64
#define SH     (TILE_H + 2 * PAD)
#define SW2    80
#define NTHREADS 512

__device__ __forceinline__ int reflect_idx(int i) {
    i = i < 0 ? -i : i;
    return i > IMG - 1 ? 2 * (IMG - 1) - i : i;
}

__global__ __launch_bounds__(NTHREADS, 8)
void dark_channel_fused(const float* __restrict__ x, float* __restrict__ out) {
    __shared__ float smin[SH][SW2];
    const int tid = threadIdx.x;
    const int bx  = blockIdx.x;
    const int by  = blockIdx.y;
    const int b   = blockIdx.z;
    const int base  = b * 3 * CH_STRIDE;
    const int row0  = by * TILE_H - PAD;
    const int col0a = bx * TILE_W - (PAD + 1);

    #pragma unroll
    for (int it = 0; it < 4; ++it) {
        int idx = tid + it * NTHREADS;
        if (idx < SH * 20) {
            int r  = idx / 20;
            int c4 = idx - r * 20;
            int gr = reflect_idx(row0 + r);
            int gc = col0a + 4 * c4;
            float4 v;
            if (gc >= 0 && gc <= IMG - 4) {
                int off = base + gr * IMG + gc;
                float4 a  = *(const float4*)(x + off);
                float4 bb = *(const float4*)(x + off + CH_STRIDE);
                float4 cc = *(const float4*)(x + off + 2 * CH_STRIDE);
                v = fmin4(fmin4(a, bb), cc);
            } else {
                #pragma unroll
                for (int j = 0; j < 4; ++j) {
                    int g   = reflect_idx(gc + j);
                    int off = base + gr * IMG + g;
                    float m = fminf(fminf(x[off], x[off + CH_STRIDE]), x[off + 2 * CH_STRIDE]);
                    if (j == 0) v.x = m; else if (j == 1) v.y = m;
                    else if (j == 2) v.z = m; else v.w = m;
                }
            }
            *(float4*)&smin[r][4 * c4] = v;
        }
    }
    __syncthreads();

    float4 h0, h1, h2;
    #pragma unroll
    for (int it = 0; it < 3; ++it) {
        int idx = tid + it * NTHREADS;
        if (idx < SH * 16) {
            int r  = idx >> 4;
            int c4 = idx & 15;
            const float* rowp = &smin[r][4 * c4];
            float4 v0 = *(const float4*)(rowp);
            float4 v1 = *(const float4*)(rowp + 4);
            float4 v2 = *(const float4*)(rowp + 8);
            float4 v3 = *(const float4*)(rowp + 12);
            float4 v4 = *(const float4*)(rowp + 16);
            float4 o  = hgroup(v0, v1, v2, v3, v4);
            // note: hgroup == previous inline math
            if (it == 0) h0 = o; else if (it == 1) h1 = o; else h2 = o;
        }
    }
    __syncthreads();

    #pragma unroll
    for (int it = 0; it < 3; ++it) {
        int idx = tid + it * NTHREADS;
        if (idx < SH * 16) {
            int r  = idx >> 4;
            int c4 = idx & 15;
            float4 o = (it == 0) ? h0 : (it == 1) ? h1 : h2;
            *(float4*)&smin[r][4 * c4] = o;
        }
    }
    __syncthreads();

    #pragma unroll
    for (int it = 0; it < 2; ++it) {
        int idx = tid + it * NTHREADS;
        int rg = idx >> 6;
        int c  = idx & 63;
        int rb = rg * 4;
        float w0  = smin[rb +  0][c], w1  = smin[rb +  1][c], w2  = smin[rb +  2][c];
        float w3  = smin[rb +  3][c], w4  = smin[rb +  4][c], w5  = smin[rb +  5][c];
        float w6  = smin[rb +  6][c], w7  = smin[rb +  7][c], w8  = smin[rb +  8][c];
        float w9  = smin[rb +  9][c], w10 = smin[rb + 10][c], w11 = smin[rb + 11][c];
        float w12 = smin[rb + 12][c], w13 = smin[rb + 13][c], w14 = smin[rb + 14][c];
        float w15 = smin[rb + 15][c], w16 = smin[rb + 16][c], w17 = smin[rb + 17][c];
        float ca = fminf(fminf(w3, w4),  fminf(w5, w6));
        float cb = fminf(fminf(w7, w8),  fminf(w9, w10));
        float cc = fminf(fminf(w11, w12), fminf(w13, w14));
        float common = fminf(ca, fminf(cb, cc));
        float p = fminf(w1, w2);
        float s = fminf(w15, w16);
        int obase = b * CH_STRIDE + (by * TILE_H + rb) * IMG + bx * TILE_W + c;
        out[obase]           = fminf(common, fminf(w0, p));
        out[obase + IMG]     = fminf(common, fminf(p, w15));
        out[obase + 2 * IMG] = fminf(common, fminf(w2, s));
        out[obase + 3 * IMG] = fminf(common, fminf(s, w17));
    }
}

extern "C" void kernel_launch(void* const* d_in, const int* in_sizes, int n_in,
                              void* d_out, int out_size, void* d_ws, size_t ws_size,
                              hipStream_t stream) {
    const float* x = (const float*)d_in[0];
    float* out = (float*)d_out;
    const size_t need = (size_t)16 * CH_STRIDE * sizeof(float);  // 16.8 MB
    if (ws_size >= need && d_ws != nullptr) {
        float* hm = (float*)d_ws;
        hpass<<<dim3(16 * 512 * 64 / 256), dim3(256), 0, stream>>>(x, hm);
        vpass<<<dim3(4, 16, 16), dim3(256), 0, stream>>>(hm, out);
    } else {
        dim3 grid(IMG / TILE_W, IMG / TILE_H, 16);
        dark_channel_fused<<<grid, dim3(NTHREADS), 0, stream>>>(x, out);
    }
}